// Round 12
// baseline (196.620 us; speedup 1.0000x reference)
//
#include <hip/hip_runtime.h>
#include <hip/hip_bf16.h>
#include <stdint.h>
#include <stddef.h>

// out = x*U + 1*c^T,  Ut = U^T = (1/32)(Tt Wq),  c = (1/32) Tt bq,
// Tt = T^T, T = K^T V = Wk G Wv^T + (Wk s) bv^T + bk (Wv s)^T + N bk bv^T,
// G = x^T x (HxH, symmetric), s = colsum(x).
// r2: per-block __threadfence banned. r3: fence-free 8 disp 212.
// r4: W2T algebra 7 disp 199.7. r5: symmetric G 195.3. r7: per-lane direct
// operand loads banned. r8: 6 disp 192.2. r9/r10: occupancy/BK experiments
// regressed (not latency- or barrier-bound). r11: diag-B-skip 191.5 (BEST).
// r12: dispatch-packing — W2T + q1 blocks move from D2 (where they formed a
// ~5us serial tail behind the 576 G blocks) to D3 (544-block short dispatch;
// they start at t=0 and hide under reduce_sym). Identical block bodies;
// only dispatch membership changes. W2T/q1 first consumed in D5.
typedef __bf16 bf16_t;
typedef __bf16 bf16x4 __attribute__((ext_vector_type(4)));
typedef __bf16 bf16x8 __attribute__((ext_vector_type(8)));
typedef float  floatx4 __attribute__((ext_vector_type(4)));

#define TK 32

// D1 (256 thr): [0,256) Wk cast+transpose -> Wkb,WkTb; [256,512) Wq
// transpose -> WqTb; [512,1536) Wv cast; [1536,3584) prep_x: cast xb,
// transpose-cast xbT, per-tile colsums -> spart[128][1024].
__global__ void prep_all(const float* __restrict__ x, bf16_t* __restrict__ xb,
                         bf16_t* __restrict__ xbT, float* __restrict__ spart,
                         const float* __restrict__ Wk, bf16_t* __restrict__ Wkb,
                         bf16_t* __restrict__ WkTb,
                         const float* __restrict__ Wv, bf16_t* __restrict__ Wvb,
                         const float* __restrict__ Wq, bf16_t* __restrict__ WqTb,
                         int SEQ, int H) {
    __shared__ __align__(16) char smem[9472];
    const int b = blockIdx.x;
    const int t = threadIdx.x;
    if (b < 512) {
        bf16_t (*tile)[72] = (bf16_t(*)[72])smem;
        const bool isK = (b < 256);
        const int bb = b & 255;
        const float* src = isK ? Wk : Wq;
        bf16_t* dT = isK ? WkTb : WqTb;
        const int r0 = (bb >> 4) * 64, c0 = (bb & 15) * 64;
        const int c4 = t & 15;
        const int rbase = t >> 4;
        #pragma unroll
        for (int p = 0; p < 4; ++p) {
            const int r = rbase + 16 * p;
            const size_t gidx = (size_t)(r0 + r) * 1024 + c0 + c4 * 4;
            float4 f = *(const float4*)(src + gidx);
            bf16x4 o;
            o.x = (bf16_t)f.x; o.y = (bf16_t)f.y;
            o.z = (bf16_t)f.z; o.w = (bf16_t)f.w;
            if (isK) *(bf16x4*)(Wkb + gidx) = o;
            *(bf16x4*)&tile[r][c4 * 4] = o;
        }
        __syncthreads();
        #pragma unroll
        for (int p = 0; p < 2; ++p) {
            const int q = t + 256 * p;
            const int cc = q >> 3;
            const int r8 = (q & 7) * 8;
            bf16x8 v;
            #pragma unroll
            for (int u = 0; u < 8; ++u) v[u] = tile[r8 + u][cc];
            *(bf16x8*)(dT + (size_t)(c0 + cc) * 1024 + r0 + r8) = v;
        }
        return;
    }
    if (b < 1536) {
        const int base = (b - 512) * 1024 + t * 4;
        float4 f = *(const float4*)(Wv + base);
        bf16x4 o;
        o.x = (bf16_t)f.x; o.y = (bf16_t)f.y;
        o.z = (bf16_t)f.z; o.w = (bf16_t)f.w;
        *(bf16x4*)(Wvb + base) = o;
        return;
    }
    bf16_t (*tile)[72] = (bf16_t(*)[72])smem;
    float* csum = (float*)(smem + 9216);
    const int LL = b - 1536;
    const int n0 = (LL >> 4) * 64, k0 = (LL & 15) * 64;
    const int c4 = t & 15;
    const int rbase = t >> 4;
    float a0 = 0.f, a1 = 0.f, a2 = 0.f, a3 = 0.f;
    if (t < 64) csum[t] = 0.f;
    #pragma unroll
    for (int p = 0; p < 4; ++p) {
        const int r = rbase + 16 * p;
        const size_t gidx = (size_t)(n0 + r) * H + k0 + c4 * 4;
        float4 f = *(const float4*)(x + gidx);
        bf16x4 o;
        o.x = (bf16_t)f.x; o.y = (bf16_t)f.y;
        o.z = (bf16_t)f.z; o.w = (bf16_t)f.w;
        *(bf16x4*)(xb + gidx) = o;
        *(bf16x4*)&tile[r][c4 * 4] = o;
        a0 += f.x; a1 += f.y; a2 += f.z; a3 += f.w;
    }
    __syncthreads();
    atomicAdd(&csum[c4 * 4 + 0], a0);
    atomicAdd(&csum[c4 * 4 + 1], a1);
    atomicAdd(&csum[c4 * 4 + 2], a2);
    atomicAdd(&csum[c4 * 4 + 3], a3);
    #pragma unroll
    for (int p = 0; p < 2; ++p) {
        const int q = t + 256 * p;
        const int kk = q >> 3;
        const int n8 = (q & 7) * 8;
        bf16x8 v;
        #pragma unroll
        for (int u = 0; u < 8; ++u) v[u] = tile[n8 + u][kk];
        *(bf16x8*)(xbT + (size_t)(k0 + kk) * SEQ + n0 + n8) = v;
    }
    __syncthreads();
    if (t < 64) spart[(n0 >> 6) * 1024 + k0 + t] = csum[t];
}

// D2 (256 thr): [0,576) G = x^T x upper-triangle 128^2 tiles, split-16
// (SWZ5; diagonal tiles skip B staging, bg reads As) -> bf16 partials;
// [576,580) svec[k] = sum_c spart.
__global__ __launch_bounds__(256, 2) void gemm_g(
    const bf16_t* __restrict__ xbT, bf16_t* __restrict__ part,
    const float* __restrict__ spart, float* __restrict__ svec)
{
    __shared__ __align__(16) char smem[16384];
    const int L = blockIdx.x;
    const int t = threadIdx.x;
    const int lane = t & 63, wave = t >> 6;
    const int wm = wave >> 1, wn = wave & 1;
    const int fr = lane & 15, fk = (lane >> 4) * 8;

    if (L < 576) {
        bf16_t* As = (bf16_t*)smem;
        bf16_t* Bs = (bf16_t*)(smem + 8192);
        const int z = ((L & 7) << 1) | (L >= 288 ? 1 : 0);
        int t36 = (L >> 3) % 36;
        int ti = 0;
        while (t36 >= 8 - ti) { t36 -= 8 - ti; ++ti; }
        const int bm = ti * 128, bn = (ti + t36) * 128;
        const int k0 = z * 512;
        bf16_t* C = part + (size_t)z * 1024 * 1024;
        floatx4 acc[4][4] = {};
        const bf16_t* Bsrc = (bm == bn) ? As : Bs;
        for (int kt = k0; kt < k0 + 512; kt += TK) {
            #pragma unroll
            for (int p = 0; p < 2; ++p) {
                const int c = t + 256 * p;
                const int r = c >> 2, o = (c & 3) * 8;
                __builtin_amdgcn_global_load_lds(
                    (const __attribute__((address_space(1))) void*)
                        (xbT + (size_t)(bm + r) * 8192 + kt + o),
                    (__attribute__((address_space(3))) void*)&As[c * 8], 16, 0, 0);
            }
            if (bm != bn) {
                #pragma unroll
                for (int p = 0; p < 2; ++p) {
                    const int c = t + 256 * p;
                    const int r = c >> 2, o = (c & 3) * 8;
                    __builtin_amdgcn_global_load_lds(
                        (const __attribute__((address_space(1))) void*)
                            (xbT + (size_t)(bn + r) * 8192 + kt + o),
                        (__attribute__((address_space(3))) void*)&Bs[c * 8], 16, 0, 0);
                }
            }
            __syncthreads();
            bf16x8 af[4], bg[4];
            #pragma unroll
            for (int i = 0; i < 4; ++i)
                af[i] = *(const bf16x8*)&As[(wm * 64 + i * 16 + fr) * TK + fk];
            #pragma unroll
            for (int j = 0; j < 4; ++j)
                bg[j] = *(const bf16x8*)&Bsrc[(wn * 64 + j * 16 + fr) * TK + fk];
            #pragma unroll
            for (int i = 0; i < 4; ++i) {
                #pragma unroll
                for (int j = 0; j < 4; ++j) {
                    acc[i][j] = __builtin_amdgcn_mfma_f32_16x16x32_bf16(
                        af[i], bg[j], acc[i][j], 0, 0, 0);
                }
            }
            __syncthreads();
        }
        const int rq = (lane >> 4) * 4;
        #pragma unroll
        for (int i = 0; i < 4; ++i) {
            #pragma unroll
            for (int j = 0; j < 4; ++j) {
                const int col = bn + wn * 64 + j * 16 + fr;
                #pragma unroll
                for (int r = 0; r < 4; ++r) {
                    const int row = bm + wm * 64 + i * 16 + rq + r;
                    C[(size_t)row * 1024 + col] = (bf16_t)acc[i][j][r];
                }
            }
        }
        return;
    }
    // svec[k] = sum_{c<128} spart[c][k]
    const int k = (L - 576) * 256 + t;
    float s = 0.f;
    for (int c = 0; c < 128; ++c) s += spart[c * 1024 + k];
    svec[k] = s;
}

// D3 (256 thr): [0,256) W2T = WqTb @ WkTb^T (64^2 tiles — long pole, first);
// [256,544) reduce_sym (sum 16 slabs over 36 upper tiles, mirror via LDS);
// [544,800) matvec2: kv1 = Wkb.svec, wvs = Wvb.svec;
// [800,1056) q1 = WkTb @ bq (4 rows/blk).
__global__ void red_mv(const bf16_t* __restrict__ part, bf16_t* __restrict__ dst,
                       const bf16_t* __restrict__ Wkb, const bf16_t* __restrict__ Wvb,
                       const float* __restrict__ svec,
                       float* __restrict__ kv1, float* __restrict__ wvs,
                       const bf16_t* __restrict__ WqTb, const bf16_t* __restrict__ WkTb,
                       bf16_t* __restrict__ W2Tb, const float* __restrict__ bq,
                       float* __restrict__ q1) {
    __shared__ __align__(16) char smem[8192];
    const int L = blockIdx.x;
    const int t = threadIdx.x;
    const int lane = t & 63, wave = t >> 6;
    if (L < 256) {
        // W2T[l][i] = sum_j Wq[j][l] Wk[j][i]  (64^2 tile, K=1024)
        bf16_t* As = (bf16_t*)smem;
        bf16_t* Bs = (bf16_t*)(smem + 4096);
        const int bm = (L >> 4) * 64, bn = (L & 15) * 64;
        const int wm = wave >> 1, wn = wave & 1;
        const int fr = lane & 15, fk = (lane >> 4) * 8;
        floatx4 acc[2][2] = {};
        const int sr = t >> 2, so = (t & 3) * 8;
        for (int kt = 0; kt < 1024; kt += TK) {
            __builtin_amdgcn_global_load_lds(
                (const __attribute__((address_space(1))) void*)
                    (WqTb + (size_t)(bm + sr) * 1024 + kt + so),
                (__attribute__((address_space(3))) void*)&As[t * 8], 16, 0, 0);
            __builtin_amdgcn_global_load_lds(
                (const __attribute__((address_space(1))) void*)
                    (WkTb + (size_t)(bn + sr) * 1024 + kt + so),
                (__attribute__((address_space(3))) void*)&Bs[t * 8], 16, 0, 0);
            __syncthreads();
            bf16x8 af[2], bg[2];
            #pragma unroll
            for (int i = 0; i < 2; ++i)
                af[i] = *(const bf16x8*)&As[(wm * 32 + i * 16 + fr) * TK + fk];
            #pragma unroll
            for (int j = 0; j < 2; ++j)
                bg[j] = *(const bf16x8*)&Bs[(wn * 32 + j * 16 + fr) * TK + fk];
            #pragma unroll
            for (int i = 0; i < 2; ++i)
                #pragma unroll
                for (int j = 0; j < 2; ++j)
                    acc[i][j] = __builtin_amdgcn_mfma_f32_16x16x32_bf16(
                        af[i], bg[j], acc[i][j], 0, 0, 0);
            __syncthreads();
        }
        const int rq = (lane >> 4) * 4;
        #pragma unroll
        for (int i = 0; i < 2; ++i)
            #pragma unroll
            for (int j = 0; j < 2; ++j) {
                const int col = bn + wn * 32 + j * 16 + fr;
                #pragma unroll
                for (int r = 0; r < 4; ++r) {
                    const int row = bm + wm * 32 + i * 16 + rq + r;
                    W2Tb[(size_t)row * 1024 + col] = (bf16_t)acc[i][j][r];
                }
            }
        return;
    }
    if (L < 544) {
        bf16_t (*lds)[128] = (bf16_t(*)[128])smem;
        const int LL = L - 256;
        int t36 = LL >> 3;
        const int chunk = LL & 7;
        int i = 0;
        while (t36 >= 8 - i) { t36 -= 8 - i; ++i; }
        const int j = i + t36;
        const int r0 = chunk * 16;
        const int rr = t >> 4;
        const int c8 = (t & 15) * 8;
        const int row = i * 128 + r0 + rr;
        const size_t off = (size_t)row * 1024 + j * 128 + c8;
        float a8[8] = {};
        for (int z = 0; z < 16; ++z) {
            bf16x8 p = *(const bf16x8*)(part + (size_t)z * 1024 * 1024 + off);
            #pragma unroll
            for (int u = 0; u < 8; ++u) a8[u] += (float)p[u];
        }
        bf16x8 o;
        #pragma unroll
        for (int u = 0; u < 8; ++u) o[u] = (bf16_t)a8[u];
        *(bf16x8*)(dst + off) = o;
        if (i == j) return;
        *(bf16x8*)&lds[rr][c8] = o;
        __syncthreads();
        const int c = t >> 1;
        const int half = t & 1;
        bf16x8 v;
        #pragma unroll
        for (int u = 0; u < 8; ++u) v[u] = lds[half * 8 + u][c];
        *(bf16x8*)(dst + (size_t)(j * 128 + c) * 1024 + i * 128 + r0 + half * 8) = v;
        return;
    }
    if (L < 800) {
        #pragma unroll
        for (int rr = 0; rr < 2; ++rr) {
            const int row = (L - 544) * 8 + wave * 2 + rr;
            const bf16_t* mp;
            float* y;
            if (row >= 1024) { mp = Wvb + (size_t)(row - 1024) * 1024; y = wvs + row - 1024; }
            else             { mp = Wkb + (size_t)row * 1024;          y = kv1 + row; }
            float acc = 0.f;
            for (int a = lane * 8; a < 1024; a += 512) {
                bf16x8 m8 = *(const bf16x8*)(mp + a);
                #pragma unroll
                for (int u = 0; u < 8; ++u) acc += (float)m8[u] * svec[a + u];
            }
            #pragma unroll
            for (int off = 32; off; off >>= 1) acc += __shfl_down(acc, off);
            if (lane == 0) *y = acc;
        }
        return;
    }
    // q1[row] = WkTb[row] . bq  (4 rows/blk)
    const int row = (L - 800) * 4 + wave;
    const bf16_t* mp = WkTb + (size_t)row * 1024;
    float acc = 0.f;
    for (int a = lane * 8; a < 1024; a += 512) {
        bf16x8 m8 = *(const bf16x8*)(mp + a);
        #pragma unroll
        for (int u = 0; u < 8; ++u) acc += (float)m8[u] * bq[a + u];
    }
    #pragma unroll
    for (int off = 32; off; off >>= 1) acc += __shfl_down(acc, off);
    if (lane == 0) q1[row] = acc;
}

// GEMM template, 256 threads (4 waves, 2x2), BK=32, A,B LDS-staged via
// global_load_lds width-16 (r7 lesson). Verified r8 structure.
// MODE 0: v = acc*scale. MODE 1: v = acc*scale + p1[col].
// MODE 3: v = (acc + rank1)*scale.
// SWZ 2: final (512 blocks: m_tile = 8*(L&7)+((L>>3)&7), n = L>>6)
// SWZ 4: H^2 64-tile (256 blocks: bm=(L>>4)*64, bn=(L&15)*64)
// MERGE (trailing blocks, 4 rows/blk):
//  3: dual matvec: mvy0 = M0 . mvv, mvy1 = M0 . mvv2
//  4: cvec: mvy0[r] = (M0[r].mvv + e_bv[r]*(mvv3.mvv2)
//            + (e_wvs[r]+cN*e_bv[r])*(mvv4.mvv2)) * mvScale
template <int TMp, int TNp, int MODE, int SWZ, int MERGE, typename OutT>
__global__ __launch_bounds__(256, 2) void gemm_bt(
    const bf16_t* __restrict__ A, const bf16_t* __restrict__ B,
    OutT* __restrict__ C, const float* __restrict__ p1,
    int M, int N, int K, int kChunk, float scale, int ngemm,
    const float* __restrict__ e_bv, const float* __restrict__ e_kv1,
    const float* __restrict__ e_wvs, const float* __restrict__ e_bk, float cN,
    const bf16_t* __restrict__ mvM0,
    const float* __restrict__ mvv, const float* __restrict__ mvv2,
    const float* __restrict__ mvv3, const float* __restrict__ mvv4,
    float* __restrict__ mvy0, float* __restrict__ mvy1, float mvScale)
{
    const int tid = threadIdx.x;
    const int L = blockIdx.x;

    if (MERGE && L >= ngemm) {
        const int lane = tid & 63, wv = tid >> 6;
        const int row = (L - ngemm) * 4 + wv;
        const bf16_t* mp = mvM0 + (size_t)row * 1024;
        if (MERGE == 3) {
            float s1 = 0.f, s2 = 0.f;
            for (int a = lane * 8; a < 1024; a += 512) {
                bf16x8 m8 = *(const bf16x8*)(mp + a);
                #pragma unroll
                for (int u = 0; u < 8; ++u) {
                    const float m = (float)m8[u];
                    s1 += m * mvv[a + u];
                    s2 += m * mvv2[a + u];
                }
            }
            #pragma unroll
            for (int off = 32; off; off >>= 1) {
                s1 += __shfl_down(s1, off);
                s2 += __shfl_down(s2, off);
            }
            if (lane == 0) { mvy0[row] = s1; mvy1[row] = s2; }
        } else { // MERGE == 4
            float s0 = 0.f, c1 = 0.f, c2 = 0.f;
            for (int a = lane * 8; a < 1024; a += 512) {
                bf16x8 m8 = *(const bf16x8*)(mp + a);
                #pragma unroll
                for (int u = 0; u < 8; ++u) {
                    s0 += (float)m8[u] * mvv[a + u];
                    c1 += mvv3[a + u] * mvv2[a + u];
                    c2 += mvv4[a + u] * mvv2[a + u];
                }
            }
            #pragma unroll
            for (int off = 32; off; off >>= 1) {
                s0 += __shfl_down(s0, off);
                c1 += __shfl_down(c1, off);
                c2 += __shfl_down(c2, off);
            }
            if (lane == 0)
                mvy0[row] = (s0 + e_bv[row] * c1 + (e_wvs[row] + cN * e_bv[row]) * c2) * mvScale;
        }
        return;
    }

    __shared__ __align__(16) bf16_t As[TMp * TK];
    __shared__ __align__(16) bf16_t Bs[TNp * TK];
    constexpr int MF = TMp / 32;
    constexpr int NF = TNp / 32;
    constexpr int nA = TMp / 64;
    constexpr int nB = TNp / 64;

    const int lane = tid & 63;
    const int wave = tid >> 6;
    const int wm   = wave >> 1;
    const int wn   = wave & 1;

    int bm, bn;
    if (SWZ == 2) {
        bm = ((L & 7) * 8 + ((L >> 3) & 7)) * TMp;
        bn = (L >> 6) * TNp;
    } else { // SWZ == 4
        bm = (L >> 4) * TMp;
        bn = (L & 15) * TNp;
    }

    floatx4 acc[MF][NF] = {};
    const int fr = lane & 15;
    const int fk = (lane >> 4) * 8;

    for (int kt = 0; kt < kChunk; kt += TK) {
        #pragma unroll
        for (int p = 0; p < nA; ++p) {
            const int c = tid + 256 * p;
            const int r = c >> 2, o = (c & 3) * 8;
            __builtin_amdgcn_global_load_lds(
                (const __attribute__((address_space(1))) void*)
                    (A + (size_t)(bm + r) * K + kt + o),
                (__attribute__((address_space(3))) void*)&As[c * 8], 16, 0, 0);
        }
        #pragma unroll
        for (int p = 0; p < nB; ++p) {
            const int c = tid + 256 * p;
            const int r = c >> 2, o = (c & 3) * 8;
            __builtin_amdgcn_global_load_lds(
                (const __attribute__((address_space(1))) void*)
                    (B + (size_t)(bn + r) * K + kt + o),
                (__attribute__((address_space(3))) void*)&Bs[c * 8], 16, 0, 0);
        }
        __syncthreads();

        bf16x8 af[MF], bg[NF];
        #pragma unroll
        for (int i = 0; i < MF; ++i)
            af[i] = *(const bf16x8*)&As[(wm * (TMp / 2) + i * 16 + fr) * TK + fk];
        #pragma unroll
        for (int j = 0; j < NF; ++j)
            bg[j] = *(const bf16x8*)&Bs[(wn * (TNp / 2) + j * 16 + fr) * TK + fk];
        #pragma unroll
        for (int i = 0; i < MF; ++i) {
            #pragma unroll
            for (int j = 0; j < NF; ++j) {
                acc[i][j] = __builtin_amdgcn_mfma_f32_16x16x32_bf16(
                    af[i], bg[j], acc[i][j], 0, 0, 0);
            }
        }
        __syncthreads();
    }

    // C/D layout (verified): col = lane&15, row = (lane>>4)*4 + reg.
    const int rq = (lane >> 4) * 4;
    #pragma unroll
    for (int i = 0; i < MF; ++i) {
        #pragma unroll
        for (int j = 0; j < NF; ++j) {
            const int col = bn + wn * (TNp / 2) + j * 16 + fr;
            #pragma unroll
            for (int r = 0; r < 4; ++r) {
                const int row = bm + wm * (TMp / 2) + i * 16 + rq + r;
                float v = acc[i][j][r];
                if (MODE == 3)
                    v += e_bv[row] * e_kv1[col] + (e_wvs[row] + cN * e_bv[row]) * e_bk[col];
                v *= scale;
                if (MODE == 1) v += p1[col];
                C[(size_t)row * N + col] = (OutT)v;
            }
        }
    }
}

extern "C" void kernel_launch(void* const* d_in, const int* in_sizes, int n_in,
                              void* d_out, int out_size, void* d_ws, size_t ws_size,
                              hipStream_t stream) {
    const int SEQ = 8192;
    const int H   = 1024;

    const float* x  = (const float*)d_in[0];
    const float* Wq = (const float*)d_in[1];
    const float* bq = (const float*)d_in[2];
    const float* Wk = (const float*)d_in[3];
    const float* bk = (const float*)d_in[4];
    const float* Wv = (const float*)d_in[5];
    const float* bv = (const float*)d_in[6];
    float* out = (float*)d_out;

    // Workspace: [0,16)Mi xb  [16,32)Mi xbT  [32,34)Mi Wkb  [34,36)Mi Wvb
    // [36,38)Mi WqTb  [38,40)Mi Gb  [40,42)Mi S1b  [42,44)Mi W2Tb
    // [44,46)Mi Utb   46Mi+: svec,kv1,wvs,cvec,q1,r1,r2 (fp32 H each)
    // [48,80)Mi: bf16 split-K partials (16 x 2 MiB, G upper tiles)
    // [80,82)Mi WkTb  [82,82.5)Mi spart (128x1024 fp32).
    const size_t MI = 1024 * 1024;
    char* ws = (char*)d_ws;
    bf16_t* xb   = (bf16_t*)(ws);
    bf16_t* xbT  = (bf16_t*)(ws + 16 * MI);
    bf16_t* Wkb  = (bf16_t*)(ws + 32 * MI);
    bf16_t* Wvb  = (bf16_t*)(ws + 34 * MI);
    bf16_t* WqTb = (bf16_t*)(ws + 36 * MI);
    bf16_t* Gb   = (bf16_t*)(ws + 38 * MI);
    bf16_t* S1b  = (bf16_t*)(ws + 40 * MI);
    bf16_t* W2Tb = (bf16_t*)(ws + 42 * MI);
    bf16_t* Utb  = (bf16_t*)(ws + 44 * MI);
    float*  svec = (float*)(ws + 46 * MI);
    float*  kv1  = svec + 1024;
    float*  wvs  = svec + 2048;
    float*  cvec = svec + 3072;
    float*  q1   = svec + 4096;
    float*  r1   = svec + 5120;
    float*  r2   = svec + 6144;
    bf16_t* part = (bf16_t*)(ws + 48 * MI);
    bf16_t* WkTb = (bf16_t*)(ws + 80 * MI);
    float*  spart = (float*)(ws + 82 * MI);

    const float inv32 = 1.0f / 32.0f;
    const float* nf = nullptr;
    float* nfm = nullptr;

    // D1: weight casts/transposes + x cast/transpose/colsum-partials
    prep_all<<<dim3(3584), dim3(256), 0, stream>>>(
        x, xb, xbT, spart, Wk, Wkb, WkTb, Wv, Wvb, Wq, WqTb, SEQ, H);
    // D2: G partials (576, SWZ5, diag-B-skip) + svec finalize (4)
    gemm_g<<<dim3(580), dim3(256), 0, stream>>>(xbT, part, spart, svec);
    // D3: W2T (256, first) + reduce_sym (288) + matvec2 (256) + q1 (256)
    red_mv<<<dim3(1056), dim3(256), 0, stream>>>(
        part, Gb, Wkb, Wvb, svec, kv1, wvs, WqTb, WkTb, W2Tb, bq, q1);
    // D4: S1 = Wv G (256 gemm) + dual matvec (256: r1 = Wq^T kv1, r2 = Wq^T bk)
    gemm_bt<64, 64, 0, 4, 3, bf16_t><<<dim3(512), dim3(256), 0, stream>>>(
        Wvb, Gb, S1b, nf, H, H, H, H, 1.0f, 256,
        nf, nf, nf, nf, 0.f, WqTb, kv1, bk, nf, nf, r1, r2, 1.0f);
    // D5: Ut = (1/32)(S1 @ W2T^T + bv r1^T + (wvs + N bv) r2^T) (256 gemm)
    //     + cvec = (1/32)(S1 q1 + bv (kv1.bq) + (wvs+N bv)(bk.bq)) (256)
    gemm_bt<64, 64, 3, 4, 4, bf16_t><<<dim3(512), dim3(256), 0, stream>>>(
        S1b, W2Tb, Utb, nf, H, H, H, H, inv32, 256,
        bv, r1, wvs, r2, (float)SEQ, S1b, q1, bq, kv1, bk, cvec, nfm, inv32);
    // D6: out = xb Ut^T + cvec (fp32; XCD-swizzled)
    gemm_bt<128, 128, 1, 2, 0, float><<<dim3(512), dim3(256), 0, stream>>>(
        xb, Utb, out, cvec, SEQ, H, H, H, 1.0f, 1 << 30,
        nf, nf, nf, nf, 0.f, nullptr, nf, nf, nf, nf, nfm, nfm, 0.f);
}

// Round 13
// 192.275 us; speedup vs baseline: 1.0226x; 1.0226x over previous
//
#include <hip/hip_runtime.h>
#include <hip/hip_bf16.h>
#include <stdint.h>
#include <stddef.h>

// out = x*U + 1*c^T,  Ut = U^T = (1/32)(Tt Wq),  c = (1/32) Tt bq,
// Tt = T^T, T = K^T V = Wk G Wv^T + (Wk s) bv^T + bk (Wv s)^T + N bk bv^T,
// G = x^T x (HxH, symmetric), s = colsum(x).
// r2: per-block __threadfence banned. r3: fence-free 8 disp 212.
// r4: W2T algebra 7 disp 199.7. r5: symmetric G 195.3. r7: per-lane direct
// operand loads banned. r8: 6 disp 192.2. r9/r10: occupancy/BK experiments
// regressed (not latency- or barrier-bound). r11: diag-B-skip 191.5 (BEST).
// r12 lesson: moving W2T/q1 from D2-tail to D3 regressed (196.6) — trailing
// merge blocks in a long oversubscribed dispatch back-fill retiring CUs and
// are already hidden; a short dispatch exposes them as the long pole.
// r13: byte-for-byte revert to r11 (verified best).
typedef __bf16 bf16_t;
typedef __bf16 bf16x4 __attribute__((ext_vector_type(4)));
typedef __bf16 bf16x8 __attribute__((ext_vector_type(8)));
typedef float  floatx4 __attribute__((ext_vector_type(4)));

#define TK 32

// D1 (256 thr): [0,256) Wk cast+transpose -> Wkb,WkTb; [256,512) Wq
// transpose -> WqTb; [512,1536) Wv cast; [1536,3584) prep_x: cast xb,
// transpose-cast xbT, per-tile colsums -> spart[128][1024].
__global__ void prep_all(const float* __restrict__ x, bf16_t* __restrict__ xb,
                         bf16_t* __restrict__ xbT, float* __restrict__ spart,
                         const float* __restrict__ Wk, bf16_t* __restrict__ Wkb,
                         bf16_t* __restrict__ WkTb,
                         const float* __restrict__ Wv, bf16_t* __restrict__ Wvb,
                         const float* __restrict__ Wq, bf16_t* __restrict__ WqTb,
                         int SEQ, int H) {
    __shared__ __align__(16) char smem[9472];
    const int b = blockIdx.x;
    const int t = threadIdx.x;
    if (b < 512) {
        bf16_t (*tile)[72] = (bf16_t(*)[72])smem;
        const bool isK = (b < 256);
        const int bb = b & 255;
        const float* src = isK ? Wk : Wq;
        bf16_t* dT = isK ? WkTb : WqTb;
        const int r0 = (bb >> 4) * 64, c0 = (bb & 15) * 64;
        const int c4 = t & 15;
        const int rbase = t >> 4;
        #pragma unroll
        for (int p = 0; p < 4; ++p) {
            const int r = rbase + 16 * p;
            const size_t gidx = (size_t)(r0 + r) * 1024 + c0 + c4 * 4;
            float4 f = *(const float4*)(src + gidx);
            bf16x4 o;
            o.x = (bf16_t)f.x; o.y = (bf16_t)f.y;
            o.z = (bf16_t)f.z; o.w = (bf16_t)f.w;
            if (isK) *(bf16x4*)(Wkb + gidx) = o;
            *(bf16x4*)&tile[r][c4 * 4] = o;
        }
        __syncthreads();
        #pragma unroll
        for (int p = 0; p < 2; ++p) {
            const int q = t + 256 * p;
            const int cc = q >> 3;
            const int r8 = (q & 7) * 8;
            bf16x8 v;
            #pragma unroll
            for (int u = 0; u < 8; ++u) v[u] = tile[r8 + u][cc];
            *(bf16x8*)(dT + (size_t)(c0 + cc) * 1024 + r0 + r8) = v;
        }
        return;
    }
    if (b < 1536) {
        const int base = (b - 512) * 1024 + t * 4;
        float4 f = *(const float4*)(Wv + base);
        bf16x4 o;
        o.x = (bf16_t)f.x; o.y = (bf16_t)f.y;
        o.z = (bf16_t)f.z; o.w = (bf16_t)f.w;
        *(bf16x4*)(Wvb + base) = o;
        return;
    }
    bf16_t (*tile)[72] = (bf16_t(*)[72])smem;
    float* csum = (float*)(smem + 9216);
    const int LL = b - 1536;
    const int n0 = (LL >> 4) * 64, k0 = (LL & 15) * 64;
    const int c4 = t & 15;
    const int rbase = t >> 4;
    float a0 = 0.f, a1 = 0.f, a2 = 0.f, a3 = 0.f;
    if (t < 64) csum[t] = 0.f;
    #pragma unroll
    for (int p = 0; p < 4; ++p) {
        const int r = rbase + 16 * p;
        const size_t gidx = (size_t)(n0 + r) * H + k0 + c4 * 4;
        float4 f = *(const float4*)(x + gidx);
        bf16x4 o;
        o.x = (bf16_t)f.x; o.y = (bf16_t)f.y;
        o.z = (bf16_t)f.z; o.w = (bf16_t)f.w;
        *(bf16x4*)(xb + gidx) = o;
        *(bf16x4*)&tile[r][c4 * 4] = o;
        a0 += f.x; a1 += f.y; a2 += f.z; a3 += f.w;
    }
    __syncthreads();
    atomicAdd(&csum[c4 * 4 + 0], a0);
    atomicAdd(&csum[c4 * 4 + 1], a1);
    atomicAdd(&csum[c4 * 4 + 2], a2);
    atomicAdd(&csum[c4 * 4 + 3], a3);
    #pragma unroll
    for (int p = 0; p < 2; ++p) {
        const int q = t + 256 * p;
        const int kk = q >> 3;
        const int n8 = (q & 7) * 8;
        bf16x8 v;
        #pragma unroll
        for (int u = 0; u < 8; ++u) v[u] = tile[n8 + u][kk];
        *(bf16x8*)(xbT + (size_t)(k0 + kk) * SEQ + n0 + n8) = v;
    }
    __syncthreads();
    if (t < 64) spart[(n0 >> 6) * 1024 + k0 + t] = csum[t];
}

// D2 (256 thr): [0,576) G = x^T x upper-triangle 128^2 tiles, split-16
// (SWZ5; diagonal tiles skip B staging, bg reads As) -> bf16 partials;
// [576,832) W2T = WqTb @ WkTb^T (64^2); [832,1088) q1 = WkTb @ bq;
// [1088,1092) svec[k] = sum_c spart.
__global__ __launch_bounds__(256, 2) void gemm_g(
    const bf16_t* __restrict__ xbT, bf16_t* __restrict__ part,
    const bf16_t* __restrict__ WqTb, const bf16_t* __restrict__ WkTb,
    bf16_t* __restrict__ W2Tb, const float* __restrict__ bq,
    float* __restrict__ q1, const float* __restrict__ spart,
    float* __restrict__ svec)
{
    __shared__ __align__(16) char smem[16384];
    const int L = blockIdx.x;
    const int t = threadIdx.x;
    const int lane = t & 63, wave = t >> 6;
    const int wm = wave >> 1, wn = wave & 1;
    const int fr = lane & 15, fk = (lane >> 4) * 8;

    if (L < 576) {
        bf16_t* As = (bf16_t*)smem;
        bf16_t* Bs = (bf16_t*)(smem + 8192);
        const int z = ((L & 7) << 1) | (L >= 288 ? 1 : 0);
        int t36 = (L >> 3) % 36;
        int ti = 0;
        while (t36 >= 8 - ti) { t36 -= 8 - ti; ++ti; }
        const int bm = ti * 128, bn = (ti + t36) * 128;
        const int k0 = z * 512;
        bf16_t* C = part + (size_t)z * 1024 * 1024;
        floatx4 acc[4][4] = {};
        const bf16_t* Bsrc = (bm == bn) ? As : Bs;
        for (int kt = k0; kt < k0 + 512; kt += TK) {
            #pragma unroll
            for (int p = 0; p < 2; ++p) {
                const int c = t + 256 * p;
                const int r = c >> 2, o = (c & 3) * 8;
                __builtin_amdgcn_global_load_lds(
                    (const __attribute__((address_space(1))) void*)
                        (xbT + (size_t)(bm + r) * 8192 + kt + o),
                    (__attribute__((address_space(3))) void*)&As[c * 8], 16, 0, 0);
            }
            if (bm != bn) {
                #pragma unroll
                for (int p = 0; p < 2; ++p) {
                    const int c = t + 256 * p;
                    const int r = c >> 2, o = (c & 3) * 8;
                    __builtin_amdgcn_global_load_lds(
                        (const __attribute__((address_space(1))) void*)
                            (xbT + (size_t)(bn + r) * 8192 + kt + o),
                        (__attribute__((address_space(3))) void*)&Bs[c * 8], 16, 0, 0);
                }
            }
            __syncthreads();
            bf16x8 af[4], bg[4];
            #pragma unroll
            for (int i = 0; i < 4; ++i)
                af[i] = *(const bf16x8*)&As[(wm * 64 + i * 16 + fr) * TK + fk];
            #pragma unroll
            for (int j = 0; j < 4; ++j)
                bg[j] = *(const bf16x8*)&Bsrc[(wn * 64 + j * 16 + fr) * TK + fk];
            #pragma unroll
            for (int i = 0; i < 4; ++i) {
                #pragma unroll
                for (int j = 0; j < 4; ++j) {
                    acc[i][j] = __builtin_amdgcn_mfma_f32_16x16x32_bf16(
                        af[i], bg[j], acc[i][j], 0, 0, 0);
                }
            }
            __syncthreads();
        }
        const int rq = (lane >> 4) * 4;
        #pragma unroll
        for (int i = 0; i < 4; ++i) {
            #pragma unroll
            for (int j = 0; j < 4; ++j) {
                const int col = bn + wn * 64 + j * 16 + fr;
                #pragma unroll
                for (int r = 0; r < 4; ++r) {
                    const int row = bm + wm * 64 + i * 16 + rq + r;
                    C[(size_t)row * 1024 + col] = (bf16_t)acc[i][j][r];
                }
            }
        }
        return;
    }
    if (L < 832) {
        // W2T[l][i] = sum_j Wq[j][l] Wk[j][i]  (64^2 tile, K=1024)
        bf16_t* As = (bf16_t*)smem;
        bf16_t* Bs = (bf16_t*)(smem + 4096);
        const int LL = L - 576;
        const int bm = (LL >> 4) * 64, bn = (LL & 15) * 64;
        floatx4 acc[2][2] = {};
        const int sr = t >> 2, so = (t & 3) * 8;
        for (int kt = 0; kt < 1024; kt += TK) {
            __builtin_amdgcn_global_load_lds(
                (const __attribute__((address_space(1))) void*)
                    (WqTb + (size_t)(bm + sr) * 1024 + kt + so),
                (__attribute__((address_space(3))) void*)&As[t * 8], 16, 0, 0);
            __builtin_amdgcn_global_load_lds(
                (const __attribute__((address_space(1))) void*)
                    (WkTb + (size_t)(bn + sr) * 1024 + kt + so),
                (__attribute__((address_space(3))) void*)&Bs[t * 8], 16, 0, 0);
            __syncthreads();
            bf16x8 af[2], bg[2];
            #pragma unroll
            for (int i = 0; i < 2; ++i)
                af[i] = *(const bf16x8*)&As[(wm * 32 + i * 16 + fr) * TK + fk];
            #pragma unroll
            for (int j = 0; j < 2; ++j)
                bg[j] = *(const bf16x8*)&Bs[(wn * 32 + j * 16 + fr) * TK + fk];
            #pragma unroll
            for (int i = 0; i < 2; ++i)
                #pragma unroll
                for (int j = 0; j < 2; ++j)
                    acc[i][j] = __builtin_amdgcn_mfma_f32_16x16x32_bf16(
                        af[i], bg[j], acc[i][j], 0, 0, 0);
            __syncthreads();
        }
        const int rq = (lane >> 4) * 4;
        #pragma unroll
        for (int i = 0; i < 2; ++i)
            #pragma unroll
            for (int j = 0; j < 2; ++j) {
                const int col = bn + wn * 32 + j * 16 + fr;
                #pragma unroll
                for (int r = 0; r < 4; ++r) {
                    const int row = bm + wm * 32 + i * 16 + rq + r;
                    W2Tb[(size_t)row * 1024 + col] = (bf16_t)acc[i][j][r];
                }
            }
        return;
    }
    if (L < 1088) {
        // q1[row] = WkTb[row] . bq  (4 rows/blk)
        const int row = (L - 832) * 4 + wave;
        const bf16_t* mp = WkTb + (size_t)row * 1024;
        float acc = 0.f;
        for (int a = lane * 8; a < 1024; a += 512) {
            bf16x8 m8 = *(const bf16x8*)(mp + a);
            #pragma unroll
            for (int u = 0; u < 8; ++u) acc += (float)m8[u] * bq[a + u];
        }
        #pragma unroll
        for (int off = 32; off; off >>= 1) acc += __shfl_down(acc, off);
        if (lane == 0) q1[row] = acc;
        return;
    }
    // svec[k] = sum_{c<128} spart[c][k]
    const int k = (L - 1088) * 256 + t;
    float s = 0.f;
    for (int c = 0; c < 128; ++c) s += spart[c * 1024 + k];
    svec[k] = s;
}

// D3 (256 thr): [0,288) reduce_sym (sum 16 slabs over 36 upper tiles,
// mirror via LDS); [288,544) matvec2: kv1 = Wkb.svec, wvs = Wvb.svec.
__global__ void red_mv(const bf16_t* __restrict__ part, bf16_t* __restrict__ dst,
                       const bf16_t* __restrict__ Wkb, const bf16_t* __restrict__ Wvb,
                       const float* __restrict__ svec,
                       float* __restrict__ kv1, float* __restrict__ wvs) {
    __shared__ bf16_t lds[16][128];
    const int L = blockIdx.x;
    const int t = threadIdx.x;
    if (L < 288) {
        int t36 = L >> 3;
        const int chunk = L & 7;
        int i = 0;
        while (t36 >= 8 - i) { t36 -= 8 - i; ++i; }
        const int j = i + t36;
        const int r0 = chunk * 16;
        const int rr = t >> 4;
        const int c8 = (t & 15) * 8;
        const int row = i * 128 + r0 + rr;
        const size_t off = (size_t)row * 1024 + j * 128 + c8;
        float a8[8] = {};
        for (int z = 0; z < 16; ++z) {
            bf16x8 p = *(const bf16x8*)(part + (size_t)z * 1024 * 1024 + off);
            #pragma unroll
            for (int u = 0; u < 8; ++u) a8[u] += (float)p[u];
        }
        bf16x8 o;
        #pragma unroll
        for (int u = 0; u < 8; ++u) o[u] = (bf16_t)a8[u];
        *(bf16x8*)(dst + off) = o;
        if (i == j) return;
        *(bf16x8*)&lds[rr][c8] = o;
        __syncthreads();
        const int c = t >> 1;
        const int half = t & 1;
        bf16x8 v;
        #pragma unroll
        for (int u = 0; u < 8; ++u) v[u] = lds[half * 8 + u][c];
        *(bf16x8*)(dst + (size_t)(j * 128 + c) * 1024 + i * 128 + r0 + half * 8) = v;
        return;
    }
    const int lane = t & 63, wv = t >> 6;
    #pragma unroll
    for (int rr = 0; rr < 2; ++rr) {
        const int row = (L - 288) * 8 + wv * 2 + rr;
        const bf16_t* mp;
        float* y;
        if (row >= 1024) { mp = Wvb + (size_t)(row - 1024) * 1024; y = wvs + row - 1024; }
        else             { mp = Wkb + (size_t)row * 1024;          y = kv1 + row; }
        float acc = 0.f;
        for (int a = lane * 8; a < 1024; a += 512) {
            bf16x8 m8 = *(const bf16x8*)(mp + a);
            #pragma unroll
            for (int u = 0; u < 8; ++u) acc += (float)m8[u] * svec[a + u];
        }
        #pragma unroll
        for (int off = 32; off; off >>= 1) acc += __shfl_down(acc, off);
        if (lane == 0) *y = acc;
    }
}

// GEMM template, 256 threads (4 waves, 2x2), BK=32, A,B LDS-staged via
// global_load_lds width-16 (r7 lesson). Verified r8 structure.
// MODE 0: v = acc*scale. MODE 1: v = acc*scale + p1[col].
// MODE 3: v = (acc + rank1)*scale.
// SWZ 2: final (512 blocks: m_tile = 8*(L&7)+((L>>3)&7), n = L>>6)
// SWZ 4: H^2 64-tile (256 blocks: bm=(L>>4)*64, bn=(L&15)*64)
// MERGE (trailing blocks, 4 rows/blk):
//  3: dual matvec: mvy0 = M0 . mvv, mvy1 = M0 . mvv2
//  4: cvec: mvy0[r] = (M0[r].mvv + e_bv[r]*(mvv3.mvv2)
//            + (e_wvs[r]+cN*e_bv[r])*(mvv4.mvv2)) * mvScale
template <int TMp, int TNp, int MODE, int SWZ, int MERGE, typename OutT>
__global__ __launch_bounds__(256, 2) void gemm_bt(
    const bf16_t* __restrict__ A, const bf16_t* __restrict__ B,
    OutT* __restrict__ C, const float* __restrict__ p1,
    int M, int N, int K, int kChunk, float scale, int ngemm,
    const float* __restrict__ e_bv, const float* __restrict__ e_kv1,
    const float* __restrict__ e_wvs, const float* __restrict__ e_bk, float cN,
    const bf16_t* __restrict__ mvM0,
    const float* __restrict__ mvv, const float* __restrict__ mvv2,
    const float* __restrict__ mvv3, const float* __restrict__ mvv4,
    float* __restrict__ mvy0, float* __restrict__ mvy1, float mvScale)
{
    const int tid = threadIdx.x;
    const int L = blockIdx.x;

    if (MERGE && L >= ngemm) {
        const int lane = tid & 63, wv = tid >> 6;
        const int row = (L - ngemm) * 4 + wv;
        const bf16_t* mp = mvM0 + (size_t)row * 1024;
        if (MERGE == 3) {
            float s1 = 0.f, s2 = 0.f;
            for (int a = lane * 8; a < 1024; a += 512) {
                bf16x8 m8 = *(const bf16x8*)(mp + a);
                #pragma unroll
                for (int u = 0; u < 8; ++u) {
                    const float m = (float)m8[u];
                    s1 += m * mvv[a + u];
                    s2 += m * mvv2[a + u];
                }
            }
            #pragma unroll
            for (int off = 32; off; off >>= 1) {
                s1 += __shfl_down(s1, off);
                s2 += __shfl_down(s2, off);
            }
            if (lane == 0) { mvy0[row] = s1; mvy1[row] = s2; }
        } else { // MERGE == 4
            float s0 = 0.f, c1 = 0.f, c2 = 0.f;
            for (int a = lane * 8; a < 1024; a += 512) {
                bf16x8 m8 = *(const bf16x8*)(mp + a);
                #pragma unroll
                for (int u = 0; u < 8; ++u) {
                    s0 += (float)m8[u] * mvv[a + u];
                    c1 += mvv3[a + u] * mvv2[a + u];
                    c2 += mvv4[a + u] * mvv2[a + u];
                }
            }
            #pragma unroll
            for (int off = 32; off; off >>= 1) {
                s0 += __shfl_down(s0, off);
                c1 += __shfl_down(c1, off);
                c2 += __shfl_down(c2, off);
            }
            if (lane == 0)
                mvy0[row] = (s0 + e_bv[row] * c1 + (e_wvs[row] + cN * e_bv[row]) * c2) * mvScale;
        }
        return;
    }

    __shared__ __align__(16) bf16_t As[TMp * TK];
    __shared__ __align__(16) bf16_t Bs[TNp * TK];
    constexpr int MF = TMp / 32;
    constexpr int NF = TNp / 32;
    constexpr int nA = TMp / 64;
    constexpr int nB = TNp / 64;

    const int lane = tid & 63;
    const int wave = tid >> 6;
    const int wm   = wave >> 1;
    const int wn   = wave & 1;

    int bm, bn;
    if (SWZ == 2) {
        bm = ((L & 7) * 8 + ((L >> 3) & 7)) * TMp;
        bn = (L >> 6) * TNp;
    } else { // SWZ == 4
        bm = (L >> 4) * TMp;
        bn = (L & 15) * TNp;
    }

    floatx4 acc[MF][NF] = {};
    const int fr = lane & 15;
    const int fk = (lane >> 4) * 8;

    for (int kt = 0; kt < kChunk; kt += TK) {
        #pragma unroll
        for (int p = 0; p < nA; ++p) {
            const int c = tid + 256 * p;
            const int r = c >> 2, o = (c & 3) * 8;
            __builtin_amdgcn_global_load_lds(
                (const __attribute__((address_space(1))) void*)
                    (A + (size_t)(bm + r) * K + kt + o),
                (__attribute__((address_space(3))) void*)&As[c * 8], 16, 0, 0);
        }
        #pragma unroll
        for (int p = 0; p < nB; ++p) {
            const int c = tid + 256 * p;
            const int r = c >> 2, o = (c & 3) * 8;
            __builtin_amdgcn_global_load_lds(
                (const __attribute__((address_space(1))) void*)
                    (B + (size_t)(bn + r) * K + kt + o),
                (__attribute__((address_space(3))) void*)&Bs[c * 8], 16, 0, 0);
        }
        __syncthreads();

        bf16x8 af[MF], bg[NF];
        #pragma unroll
        for (int i = 0; i < MF; ++i)
            af[i] = *(const bf16x8*)&As[(wm * (TMp / 2) + i * 16 + fr) * TK + fk];
        #pragma unroll
        for (int j = 0; j < NF; ++j)
            bg[j] = *(const bf16x8*)&Bs[(wn * (TNp / 2) + j * 16 + fr) * TK + fk];
        #pragma unroll
        for (int i = 0; i < MF; ++i) {
            #pragma unroll
            for (int j = 0; j < NF; ++j) {
                acc[i][j] = __builtin_amdgcn_mfma_f32_16x16x32_bf16(
                    af[i], bg[j], acc[i][j], 0, 0, 0);
            }
        }
        __syncthreads();
    }

    // C/D layout (verified): col = lane&15, row = (lane>>4)*4 + reg.
    const int rq = (lane >> 4) * 4;
    #pragma unroll
    for (int i = 0; i < MF; ++i) {
        #pragma unroll
        for (int j = 0; j < NF; ++j) {
            const int col = bn + wn * (TNp / 2) + j * 16 + fr;
            #pragma unroll
            for (int r = 0; r < 4; ++r) {
                const int row = bm + wm * (TMp / 2) + i * 16 + rq + r;
                float v = acc[i][j][r];
                if (MODE == 3)
                    v += e_bv[row] * e_kv1[col] + (e_wvs[row] + cN * e_bv[row]) * e_bk[col];
                v *= scale;
                if (MODE == 1) v += p1[col];
                C[(size_t)row * N + col] = (OutT)v;
            }
        }
    }
}

extern "C" void kernel_launch(void* const* d_in, const int* in_sizes, int n_in,
                              void* d_out, int out_size, void* d_ws, size_t ws_size,
                              hipStream_t stream) {
    const int SEQ = 8192;
    const int H   = 1024;

    const float* x  = (const float*)d_in[0];
    const float* Wq = (const float*)d_in[1];
    const float* bq = (const float*)d_in[2];
    const float* Wk = (const float*)d_in[3];
    const float* bk = (const float*)d_in[4];
    const float* Wv = (const float*)d_in[5];
    const float* bv = (const float*)d_in[6];
    float* out = (float*)d_out;

    // Workspace: [0,16)Mi xb  [16,32)Mi xbT  [32,34)Mi Wkb  [34,36)Mi Wvb
    // [36,38)Mi WqTb  [38,40)Mi Gb  [40,42)Mi S1b  [42,44)Mi W2Tb
    // [44,46)Mi Utb   46Mi+: svec,kv1,wvs,cvec,q1,r1,r2 (fp32 H each)
    // [48,80)Mi: bf16 split-K partials (16 x 2 MiB, G upper tiles)
    // [80,82)Mi WkTb  [82,82.5)Mi spart (128x1024 fp32).
    const size_t MI = 1024 * 1024;
    char* ws = (char*)d_ws;
    bf16_t* xb   = (bf16_t*)(ws);
    bf16_t* xbT  = (bf16_t*)(ws + 16 * MI);
    bf16_t* Wkb  = (bf16_t*)(ws + 32 * MI);
    bf16_t* Wvb  = (bf16_t*)(ws + 34 * MI);
    bf16_t* WqTb = (bf16_t*)(ws + 36 * MI);
    bf16_t* Gb   = (bf16_t*)(ws + 38 * MI);
    bf16_t* S1b  = (bf16_t*)(ws + 40 * MI);
    bf16_t* W2Tb = (bf16_t*)(ws + 42 * MI);
    bf16_t* Utb  = (bf16_t*)(ws + 44 * MI);
    float*  svec = (float*)(ws + 46 * MI);
    float*  kv1  = svec + 1024;
    float*  wvs  = svec + 2048;
    float*  cvec = svec + 3072;
    float*  q1   = svec + 4096;
    float*  r1   = svec + 5120;
    float*  r2   = svec + 6144;
    bf16_t* part = (bf16_t*)(ws + 48 * MI);
    bf16_t* WkTb = (bf16_t*)(ws + 80 * MI);
    float*  spart = (float*)(ws + 82 * MI);

    const float inv32 = 1.0f / 32.0f;
    const float* nf = nullptr;
    float* nfm = nullptr;

    // D1: weight casts/transposes + x cast/transpose/colsum-partials
    prep_all<<<dim3(3584), dim3(256), 0, stream>>>(
        x, xb, xbT, spart, Wk, Wkb, WkTb, Wv, Wvb, Wq, WqTb, SEQ, H);
    // D2: G partials (576, SWZ5, diag-B-skip) + W2T (256) + q1 (256) + svec (4)
    gemm_g<<<dim3(1092), dim3(256), 0, stream>>>(
        xbT, part, WqTb, WkTb, W2Tb, bq, q1, spart, svec);
    // D3: reduce_sym (288) + matvec2 (256)
    red_mv<<<dim3(544), dim3(256), 0, stream>>>(part, Gb, Wkb, Wvb, svec, kv1, wvs);
    // D4: S1 = Wv G (256 gemm) + dual matvec (256: r1 = Wq^T kv1, r2 = Wq^T bk)
    gemm_bt<64, 64, 0, 4, 3, bf16_t><<<dim3(512), dim3(256), 0, stream>>>(
        Wvb, Gb, S1b, nf, H, H, H, H, 1.0f, 256,
        nf, nf, nf, nf, 0.f, WqTb, kv1, bk, nf, nf, r1, r2, 1.0f);
    // D5: Ut = (1/32)(S1 @ W2T^T + bv r1^T + (wvs + N bv) r2^T) (256 gemm)
    //     + cvec = (1/32)(S1 q1 + bv (kv1.bq) + (wvs+N bv)(bk.bq)) (256)
    gemm_bt<64, 64, 3, 4, 4, bf16_t><<<dim3(512), dim3(256), 0, stream>>>(
        S1b, W2Tb, Utb, nf, H, H, H, H, inv32, 256,
        bv, r1, wvs, r2, (float)SEQ, S1b, q1, bq, kv1, bk, cvec, nfm, inv32);
    // D6: out = xb Ut^T + cvec (fp32; XCD-swizzled)
    gemm_bt<128, 128, 1, 2, 0, float><<<dim3(512), dim3(256), 0, stream>>>(
        xb, Utb, out, cvec, SEQ, H, H, H, 1.0f, 1 << 30,
        nf, nf, nf, nf, 0.f, nullptr, nf, nf, nf, nf, nfm, nfm, 0.f);
}

// Round 14
// 191.426 us; speedup vs baseline: 1.0271x; 1.0044x over previous
//
#include <hip/hip_runtime.h>
#include <hip/hip_bf16.h>
#include <stdint.h>
#include <stddef.h>

// out = x*U + 1*c^T,  Ut = U^T = (1/32)(Tt Wq),  c = (1/32) Tt bq,
// Tt = T^T, T = K^T V = Wk G Wv^T + (Wk s) bv^T + bk (Wv s)^T + N bk bv^T,
// G = x^T x (HxH, symmetric), s = colsum(x).
// r2: per-block __threadfence banned. r3: fence-free 8 disp 212.
// r4: W2T algebra 7 disp 199.7. r5: symmetric G 195.3. r7: per-lane direct
// operand loads banned. r8: 6 disp 192.2. r9: 512-thr blocks (2 groups x 8
// waves) neutral. r10: BK=64 neutral-negative. r11: diag-B-skip 191.5 (BEST,
// reproduced 192.3 r13 — noise band +-3us). r12: packing regressed.
// r14: __launch_bounds__(256,4) on GEMM kernels — 4 independent
// barrier-groups (blocks) per CU instead of 2. Untested quadrant of the
// occupancy family: r9 doubled waves within a block (lockstep drain);
// this doubles BLOCKS (desynchronized vmcnt drains). Register budget:
// ~60 VGPR + 64 AGPR = ~124 <= 128 (4 waves/SIMD). Math bitwise-identical.
typedef __bf16 bf16_t;
typedef __bf16 bf16x4 __attribute__((ext_vector_type(4)));
typedef __bf16 bf16x8 __attribute__((ext_vector_type(8)));
typedef float  floatx4 __attribute__((ext_vector_type(4)));

#define TK 32

// D1 (256 thr): [0,256) Wk cast+transpose -> Wkb,WkTb; [256,512) Wq
// transpose -> WqTb; [512,1536) Wv cast; [1536,3584) prep_x: cast xb,
// transpose-cast xbT, per-tile colsums -> spart[128][1024].
__global__ void prep_all(const float* __restrict__ x, bf16_t* __restrict__ xb,
                         bf16_t* __restrict__ xbT, float* __restrict__ spart,
                         const float* __restrict__ Wk, bf16_t* __restrict__ Wkb,
                         bf16_t* __restrict__ WkTb,
                         const float* __restrict__ Wv, bf16_t* __restrict__ Wvb,
                         const float* __restrict__ Wq, bf16_t* __restrict__ WqTb,
                         int SEQ, int H) {
    __shared__ __align__(16) char smem[9472];
    const int b = blockIdx.x;
    const int t = threadIdx.x;
    if (b < 512) {
        bf16_t (*tile)[72] = (bf16_t(*)[72])smem;
        const bool isK = (b < 256);
        const int bb = b & 255;
        const float* src = isK ? Wk : Wq;
        bf16_t* dT = isK ? WkTb : WqTb;
        const int r0 = (bb >> 4) * 64, c0 = (bb & 15) * 64;
        const int c4 = t & 15;
        const int rbase = t >> 4;
        #pragma unroll
        for (int p = 0; p < 4; ++p) {
            const int r = rbase + 16 * p;
            const size_t gidx = (size_t)(r0 + r) * 1024 + c0 + c4 * 4;
            float4 f = *(const float4*)(src + gidx);
            bf16x4 o;
            o.x = (bf16_t)f.x; o.y = (bf16_t)f.y;
            o.z = (bf16_t)f.z; o.w = (bf16_t)f.w;
            if (isK) *(bf16x4*)(Wkb + gidx) = o;
            *(bf16x4*)&tile[r][c4 * 4] = o;
        }
        __syncthreads();
        #pragma unroll
        for (int p = 0; p < 2; ++p) {
            const int q = t + 256 * p;
            const int cc = q >> 3;
            const int r8 = (q & 7) * 8;
            bf16x8 v;
            #pragma unroll
            for (int u = 0; u < 8; ++u) v[u] = tile[r8 + u][cc];
            *(bf16x8*)(dT + (size_t)(c0 + cc) * 1024 + r0 + r8) = v;
        }
        return;
    }
    if (b < 1536) {
        const int base = (b - 512) * 1024 + t * 4;
        float4 f = *(const float4*)(Wv + base);
        bf16x4 o;
        o.x = (bf16_t)f.x; o.y = (bf16_t)f.y;
        o.z = (bf16_t)f.z; o.w = (bf16_t)f.w;
        *(bf16x4*)(Wvb + base) = o;
        return;
    }
    bf16_t (*tile)[72] = (bf16_t(*)[72])smem;
    float* csum = (float*)(smem + 9216);
    const int LL = b - 1536;
    const int n0 = (LL >> 4) * 64, k0 = (LL & 15) * 64;
    const int c4 = t & 15;
    const int rbase = t >> 4;
    float a0 = 0.f, a1 = 0.f, a2 = 0.f, a3 = 0.f;
    if (t < 64) csum[t] = 0.f;
    #pragma unroll
    for (int p = 0; p < 4; ++p) {
        const int r = rbase + 16 * p;
        const size_t gidx = (size_t)(n0 + r) * H + k0 + c4 * 4;
        float4 f = *(const float4*)(x + gidx);
        bf16x4 o;
        o.x = (bf16_t)f.x; o.y = (bf16_t)f.y;
        o.z = (bf16_t)f.z; o.w = (bf16_t)f.w;
        *(bf16x4*)(xb + gidx) = o;
        *(bf16x4*)&tile[r][c4 * 4] = o;
        a0 += f.x; a1 += f.y; a2 += f.z; a3 += f.w;
    }
    __syncthreads();
    atomicAdd(&csum[c4 * 4 + 0], a0);
    atomicAdd(&csum[c4 * 4 + 1], a1);
    atomicAdd(&csum[c4 * 4 + 2], a2);
    atomicAdd(&csum[c4 * 4 + 3], a3);
    #pragma unroll
    for (int p = 0; p < 2; ++p) {
        const int q = t + 256 * p;
        const int kk = q >> 3;
        const int n8 = (q & 7) * 8;
        bf16x8 v;
        #pragma unroll
        for (int u = 0; u < 8; ++u) v[u] = tile[n8 + u][kk];
        *(bf16x8*)(xbT + (size_t)(k0 + kk) * SEQ + n0 + n8) = v;
    }
    __syncthreads();
    if (t < 64) spart[(n0 >> 6) * 1024 + k0 + t] = csum[t];
}

// D2 (256 thr): [0,576) G = x^T x upper-triangle 128^2 tiles, split-16
// (SWZ5; diagonal tiles skip B staging, bg reads As) -> bf16 partials;
// [576,832) W2T = WqTb @ WkTb^T (64^2); [832,1088) q1 = WkTb @ bq;
// [1088,1092) svec[k] = sum_c spart.
__global__ __launch_bounds__(256, 4) void gemm_g(
    const bf16_t* __restrict__ xbT, bf16_t* __restrict__ part,
    const bf16_t* __restrict__ WqTb, const bf16_t* __restrict__ WkTb,
    bf16_t* __restrict__ W2Tb, const float* __restrict__ bq,
    float* __restrict__ q1, const float* __restrict__ spart,
    float* __restrict__ svec)
{
    __shared__ __align__(16) char smem[16384];
    const int L = blockIdx.x;
    const int t = threadIdx.x;
    const int lane = t & 63, wave = t >> 6;
    const int wm = wave >> 1, wn = wave & 1;
    const int fr = lane & 15, fk = (lane >> 4) * 8;

    if (L < 576) {
        bf16_t* As = (bf16_t*)smem;
        bf16_t* Bs = (bf16_t*)(smem + 8192);
        const int z = ((L & 7) << 1) | (L >= 288 ? 1 : 0);
        int t36 = (L >> 3) % 36;
        int ti = 0;
        while (t36 >= 8 - ti) { t36 -= 8 - ti; ++ti; }
        const int bm = ti * 128, bn = (ti + t36) * 128;
        const int k0 = z * 512;
        bf16_t* C = part + (size_t)z * 1024 * 1024;
        floatx4 acc[4][4] = {};
        const bf16_t* Bsrc = (bm == bn) ? As : Bs;
        for (int kt = k0; kt < k0 + 512; kt += TK) {
            #pragma unroll
            for (int p = 0; p < 2; ++p) {
                const int c = t + 256 * p;
                const int r = c >> 2, o = (c & 3) * 8;
                __builtin_amdgcn_global_load_lds(
                    (const __attribute__((address_space(1))) void*)
                        (xbT + (size_t)(bm + r) * 8192 + kt + o),
                    (__attribute__((address_space(3))) void*)&As[c * 8], 16, 0, 0);
            }
            if (bm != bn) {
                #pragma unroll
                for (int p = 0; p < 2; ++p) {
                    const int c = t + 256 * p;
                    const int r = c >> 2, o = (c & 3) * 8;
                    __builtin_amdgcn_global_load_lds(
                        (const __attribute__((address_space(1))) void*)
                            (xbT + (size_t)(bn + r) * 8192 + kt + o),
                        (__attribute__((address_space(3))) void*)&Bs[c * 8], 16, 0, 0);
                }
            }
            __syncthreads();
            bf16x8 af[4], bg[4];
            #pragma unroll
            for (int i = 0; i < 4; ++i)
                af[i] = *(const bf16x8*)&As[(wm * 64 + i * 16 + fr) * TK + fk];
            #pragma unroll
            for (int j = 0; j < 4; ++j)
                bg[j] = *(const bf16x8*)&Bsrc[(wn * 64 + j * 16 + fr) * TK + fk];
            #pragma unroll
            for (int i = 0; i < 4; ++i) {
                #pragma unroll
                for (int j = 0; j < 4; ++j) {
                    acc[i][j] = __builtin_amdgcn_mfma_f32_16x16x32_bf16(
                        af[i], bg[j], acc[i][j], 0, 0, 0);
                }
            }
            __syncthreads();
        }
        const int rq = (lane >> 4) * 4;
        #pragma unroll
        for (int i = 0; i < 4; ++i) {
            #pragma unroll
            for (int j = 0; j < 4; ++j) {
                const int col = bn + wn * 64 + j * 16 + fr;
                #pragma unroll
                for (int r = 0; r < 4; ++r) {
                    const int row = bm + wm * 64 + i * 16 + rq + r;
                    C[(size_t)row * 1024 + col] = (bf16_t)acc[i][j][r];
                }
            }
        }
        return;
    }
    if (L < 832) {
        // W2T[l][i] = sum_j Wq[j][l] Wk[j][i]  (64^2 tile, K=1024)
        bf16_t* As = (bf16_t*)smem;
        bf16_t* Bs = (bf16_t*)(smem + 4096);
        const int LL = L - 576;
        const int bm = (LL >> 4) * 64, bn = (LL & 15) * 64;
        floatx4 acc[2][2] = {};
        const int sr = t >> 2, so = (t & 3) * 8;
        for (int kt = 0; kt < 1024; kt += TK) {
            __builtin_amdgcn_global_load_lds(
                (const __attribute__((address_space(1))) void*)
                    (WqTb + (size_t)(bm + sr) * 1024 + kt + so),
                (__attribute__((address_space(3))) void*)&As[t * 8], 16, 0, 0);
            __builtin_amdgcn_global_load_lds(
                (const __attribute__((address_space(1))) void*)
                    (WkTb + (size_t)(bn + sr) * 1024 + kt + so),
                (__attribute__((address_space(3))) void*)&Bs[t * 8], 16, 0, 0);
            __syncthreads();
            bf16x8 af[2], bg[2];
            #pragma unroll
            for (int i = 0; i < 2; ++i)
                af[i] = *(const bf16x8*)&As[(wm * 32 + i * 16 + fr) * TK + fk];
            #pragma unroll
            for (int j = 0; j < 2; ++j)
                bg[j] = *(const bf16x8*)&Bs[(wn * 32 + j * 16 + fr) * TK + fk];
            #pragma unroll
            for (int i = 0; i < 2; ++i)
                #pragma unroll
                for (int j = 0; j < 2; ++j)
                    acc[i][j] = __builtin_amdgcn_mfma_f32_16x16x32_bf16(
                        af[i], bg[j], acc[i][j], 0, 0, 0);
            __syncthreads();
        }
        const int rq = (lane >> 4) * 4;
        #pragma unroll
        for (int i = 0; i < 2; ++i)
            #pragma unroll
            for (int j = 0; j < 2; ++j) {
                const int col = bn + wn * 32 + j * 16 + fr;
                #pragma unroll
                for (int r = 0; r < 4; ++r) {
                    const int row = bm + wm * 32 + i * 16 + rq + r;
                    W2Tb[(size_t)row * 1024 + col] = (bf16_t)acc[i][j][r];
                }
            }
        return;
    }
    if (L < 1088) {
        // q1[row] = WkTb[row] . bq  (4 rows/blk)
        const int row = (L - 832) * 4 + wave;
        const bf16_t* mp = WkTb + (size_t)row * 1024;
        float acc = 0.f;
        for (int a = lane * 8; a < 1024; a += 512) {
            bf16x8 m8 = *(const bf16x8*)(mp + a);
            #pragma unroll
            for (int u = 0; u < 8; ++u) acc += (float)m8[u] * bq[a + u];
        }
        #pragma unroll
        for (int off = 32; off; off >>= 1) acc += __shfl_down(acc, off);
        if (lane == 0) q1[row] = acc;
        return;
    }
    // svec[k] = sum_{c<128} spart[c][k]
    const int k = (L - 1088) * 256 + t;
    float s = 0.f;
    for (int c = 0; c < 128; ++c) s += spart[c * 1024 + k];
    svec[k] = s;
}

// D3 (256 thr): [0,288) reduce_sym (sum 16 slabs over 36 upper tiles,
// mirror via LDS); [288,544) matvec2: kv1 = Wkb.svec, wvs = Wvb.svec.
__global__ void red_mv(const bf16_t* __restrict__ part, bf16_t* __restrict__ dst,
                       const bf16_t* __restrict__ Wkb, const bf16_t* __restrict__ Wvb,
                       const float* __restrict__ svec,
                       float* __restrict__ kv1, float* __restrict__ wvs) {
    __shared__ bf16_t lds[16][128];
    const int L = blockIdx.x;
    const int t = threadIdx.x;
    if (L < 288) {
        int t36 = L >> 3;
        const int chunk = L & 7;
        int i = 0;
        while (t36 >= 8 - i) { t36 -= 8 - i; ++i; }
        const int j = i + t36;
        const int r0 = chunk * 16;
        const int rr = t >> 4;
        const int c8 = (t & 15) * 8;
        const int row = i * 128 + r0 + rr;
        const size_t off = (size_t)row * 1024 + j * 128 + c8;
        float a8[8] = {};
        for (int z = 0; z < 16; ++z) {
            bf16x8 p = *(const bf16x8*)(part + (size_t)z * 1024 * 1024 + off);
            #pragma unroll
            for (int u = 0; u < 8; ++u) a8[u] += (float)p[u];
        }
        bf16x8 o;
        #pragma unroll
        for (int u = 0; u < 8; ++u) o[u] = (bf16_t)a8[u];
        *(bf16x8*)(dst + off) = o;
        if (i == j) return;
        *(bf16x8*)&lds[rr][c8] = o;
        __syncthreads();
        const int c = t >> 1;
        const int half = t & 1;
        bf16x8 v;
        #pragma unroll
        for (int u = 0; u < 8; ++u) v[u] = lds[half * 8 + u][c];
        *(bf16x8*)(dst + (size_t)(j * 128 + c) * 1024 + i * 128 + r0 + half * 8) = v;
        return;
    }
    const int lane = t & 63, wv = t >> 6;
    #pragma unroll
    for (int rr = 0; rr < 2; ++rr) {
        const int row = (L - 288) * 8 + wv * 2 + rr;
        const bf16_t* mp;
        float* y;
        if (row >= 1024) { mp = Wvb + (size_t)(row - 1024) * 1024; y = wvs + row - 1024; }
        else             { mp = Wkb + (size_t)row * 1024;          y = kv1 + row; }
        float acc = 0.f;
        for (int a = lane * 8; a < 1024; a += 512) {
            bf16x8 m8 = *(const bf16x8*)(mp + a);
            #pragma unroll
            for (int u = 0; u < 8; ++u) acc += (float)m8[u] * svec[a + u];
        }
        #pragma unroll
        for (int off = 32; off; off >>= 1) acc += __shfl_down(acc, off);
        if (lane == 0) *y = acc;
    }
}

// GEMM template, 256 threads (4 waves, 2x2), BK=32, A,B LDS-staged via
// global_load_lds width-16 (r7 lesson). Verified r8 structure; r14:
// launch_bounds (256,4) -> 4 independent blocks/CU (reg budget 128/wave).
// MODE 0: v = acc*scale. MODE 1: v = acc*scale + p1[col].
// MODE 3: v = (acc + rank1)*scale.
// SWZ 2: final (512 blocks: m_tile = 8*(L&7)+((L>>3)&7), n = L>>6)
// SWZ 4: H^2 64-tile (256 blocks: bm=(L>>4)*64, bn=(L&15)*64)
// MERGE (trailing blocks, 4 rows/blk):
//  3: dual matvec: mvy0 = M0 . mvv, mvy1 = M0 . mvv2
//  4: cvec: mvy0[r] = (M0[r].mvv + e_bv[r]*(mvv3.mvv2)
//            + (e_wvs[r]+cN*e_bv[r])*(mvv4.mvv2)) * mvScale
template <int TMp, int TNp, int MODE, int SWZ, int MERGE, typename OutT>
__global__ __launch_bounds__(256, 4) void gemm_bt(
    const bf16_t* __restrict__ A, const bf16_t* __restrict__ B,
    OutT* __restrict__ C, const float* __restrict__ p1,
    int M, int N, int K, int kChunk, float scale, int ngemm,
    const float* __restrict__ e_bv, const float* __restrict__ e_kv1,
    const float* __restrict__ e_wvs, const float* __restrict__ e_bk, float cN,
    const bf16_t* __restrict__ mvM0,
    const float* __restrict__ mvv, const float* __restrict__ mvv2,
    const float* __restrict__ mvv3, const float* __restrict__ mvv4,
    float* __restrict__ mvy0, float* __restrict__ mvy1, float mvScale)
{
    const int tid = threadIdx.x;
    const int L = blockIdx.x;

    if (MERGE && L >= ngemm) {
        const int lane = tid & 63, wv = tid >> 6;
        const int row = (L - ngemm) * 4 + wv;
        const bf16_t* mp = mvM0 + (size_t)row * 1024;
        if (MERGE == 3) {
            float s1 = 0.f, s2 = 0.f;
            for (int a = lane * 8; a < 1024; a += 512) {
                bf16x8 m8 = *(const bf16x8*)(mp + a);
                #pragma unroll
                for (int u = 0; u < 8; ++u) {
                    const float m = (float)m8[u];
                    s1 += m * mvv[a + u];
                    s2 += m * mvv2[a + u];
                }
            }
            #pragma unroll
            for (int off = 32; off; off >>= 1) {
                s1 += __shfl_down(s1, off);
                s2 += __shfl_down(s2, off);
            }
            if (lane == 0) { mvy0[row] = s1; mvy1[row] = s2; }
        } else { // MERGE == 4
            float s0 = 0.f, c1 = 0.f, c2 = 0.f;
            for (int a = lane * 8; a < 1024; a += 512) {
                bf16x8 m8 = *(const bf16x8*)(mp + a);
                #pragma unroll
                for (int u = 0; u < 8; ++u) {
                    s0 += (float)m8[u] * mvv[a + u];
                    c1 += mvv3[a + u] * mvv2[a + u];
                    c2 += mvv4[a + u] * mvv2[a + u];
                }
            }
            #pragma unroll
            for (int off = 32; off; off >>= 1) {
                s0 += __shfl_down(s0, off);
                c1 += __shfl_down(c1, off);
                c2 += __shfl_down(c2, off);
            }
            if (lane == 0)
                mvy0[row] = (s0 + e_bv[row] * c1 + (e_wvs[row] + cN * e_bv[row]) * c2) * mvScale;
        }
        return;
    }

    __shared__ __align__(16) bf16_t As[TMp * TK];
    __shared__ __align__(16) bf16_t Bs[TNp * TK];
    constexpr int MF = TMp / 32;
    constexpr int NF = TNp / 32;
    constexpr int nA = TMp / 64;
    constexpr int nB = TNp / 64;

    const int lane = tid & 63;
    const int wave = tid >> 6;
    const int wm   = wave >> 1;
    const int wn   = wave & 1;

    int bm, bn;
    if (SWZ == 2) {
        bm = ((L & 7) * 8 + ((L >> 3) & 7)) * TMp;
        bn = (L >> 6) * TNp;
    } else { // SWZ == 4
        bm = (L >> 4) * TMp;
        bn = (L & 15) * TNp;
    }

    floatx4 acc[MF][NF] = {};
    const int fr = lane & 15;
    const int fk = (lane >> 4) * 8;

    for (int kt = 0; kt < kChunk; kt += TK) {
        #pragma unroll
        for (int p = 0; p < nA; ++p) {
            const int c = tid + 256 * p;
            const int r = c >> 2, o = (c & 3) * 8;
            __builtin_amdgcn_global_load_lds(
                (const __attribute__((address_space(1))) void*)
                    (A + (size_t)(bm + r) * K + kt + o),
                (__attribute__((address_space(3))) void*)&As[c * 8], 16, 0, 0);
        }
        #pragma unroll
        for (int p = 0; p < nB; ++p) {
            const int c = tid + 256 * p;
            const int r = c >> 2, o = (c & 3) * 8;
            __builtin_amdgcn_global_load_lds(
                (const __attribute__((address_space(1))) void*)
                    (B + (size_t)(bn + r) * K + kt + o),
                (__attribute__((address_space(3))) void*)&Bs[c * 8], 16, 0, 0);
        }
        __syncthreads();

        bf16x8 af[MF], bg[NF];
        #pragma unroll
        for (int i = 0; i < MF; ++i)
            af[i] = *(const bf16x8*)&As[(wm * (TMp / 2) + i * 16 + fr) * TK + fk];
        #pragma unroll
        for (int j = 0; j < NF; ++j)
            bg[j] = *(const bf16x8*)&Bs[(wn * (TNp / 2) + j * 16 + fr) * TK + fk];
        #pragma unroll
        for (int i = 0; i < MF; ++i) {
            #pragma unroll
            for (int j = 0; j < NF; ++j) {
                acc[i][j] = __builtin_amdgcn_mfma_f32_16x16x32_bf16(
                    af[i], bg[j], acc[i][j], 0, 0, 0);
            }
        }
        __syncthreads();
    }

    // C/D layout (verified): col = lane&15, row = (lane>>4)*4 + reg.
    const int rq = (lane >> 4) * 4;
    #pragma unroll
    for (int i = 0; i < MF; ++i) {
        #pragma unroll
        for (int j = 0; j < NF; ++j) {
            const int col = bn + wn * (TNp / 2) + j * 16 + fr;
            #pragma unroll
            for (int r = 0; r < 4; ++r) {
                const int row = bm + wm * (TMp / 2) + i * 16 + rq + r;
                float v = acc[i][j][r];
                if (MODE == 3)
                    v += e_bv[row] * e_kv1[col] + (e_wvs[row] + cN * e_bv[row]) * e_bk[col];
                v *= scale;
                if (MODE == 1) v += p1[col];
                C[(size_t)row * N + col] = (OutT)v;
            }
        }
    }
}

extern "C" void kernel_launch(void* const* d_in, const int* in_sizes, int n_in,
                              void* d_out, int out_size, void* d_ws, size_t ws_size,
                              hipStream_t stream) {
    const int SEQ = 8192;
    const int H   = 1024;

    const float* x  = (const float*)d_in[0];
    const float* Wq = (const float*)d_in[1];
    const float* bq = (const float*)d_in[2];
    const float* Wk = (const float*)d_in[3];
    const float* bk = (const float*)d_in[4];
    const float* Wv = (const float*)d_in[5];
    const float* bv = (const float*)d_in[6];
    float* out = (float*)d_out;

    // Workspace: [0,16)Mi xb  [16,32)Mi xbT  [32,34)Mi Wkb  [34,36)Mi Wvb
    // [36,38)Mi WqTb  [38,40)Mi Gb  [40,42)Mi S1b  [42,44)Mi W2Tb
    // [44,46)Mi Utb   46Mi+: svec,kv1,wvs,cvec,q1,r1,r2 (fp32 H each)
    // [48,80)Mi: bf16 split-K partials (16 x 2 MiB, G upper tiles)
    // [80,82)Mi WkTb  [82,82.5)Mi spart (128x1024 fp32).
    const size_t MI = 1024 * 1024;
    char* ws = (char*)d_ws;
    bf16_t* xb   = (bf16_t*)(ws);
    bf16_t* xbT  = (bf16_t*)(ws + 16 * MI);
    bf16_t* Wkb  = (bf16_t*)(ws + 32 * MI);
    bf16_t* Wvb  = (bf16_t*)(ws + 34 * MI);
    bf16_t* WqTb = (bf16_t*)(ws + 36 * MI);
    bf16_t* Gb   = (bf16_t*)(ws + 38 * MI);
    bf16_t* S1b  = (bf16_t*)(ws + 40 * MI);
    bf16_t* W2Tb = (bf16_t*)(ws + 42 * MI);
    bf16_t* Utb  = (bf16_t*)(ws + 44 * MI);
    float*  svec = (float*)(ws + 46 * MI);
    float*  kv1  = svec + 1024;
    float*  wvs  = svec + 2048;
    float*  cvec = svec + 3072;
    float*  q1   = svec + 4096;
    float*  r1   = svec + 5120;
    float*  r2   = svec + 6144;
    bf16_t* part = (bf16_t*)(ws + 48 * MI);
    bf16_t* WkTb = (bf16_t*)(ws + 80 * MI);
    float*  spart = (float*)(ws + 82 * MI);

    const float inv32 = 1.0f / 32.0f;
    const float* nf = nullptr;
    float* nfm = nullptr;

    // D1: weight casts/transposes + x cast/transpose/colsum-partials
    prep_all<<<dim3(3584), dim3(256), 0, stream>>>(
        x, xb, xbT, spart, Wk, Wkb, WkTb, Wv, Wvb, Wq, WqTb, SEQ, H);
    // D2: G partials (576, SWZ5, diag-B-skip) + W2T (256) + q1 (256) + svec (4)
    gemm_g<<<dim3(1092), dim3(256), 0, stream>>>(
        xbT, part, WqTb, WkTb, W2Tb, bq, q1, spart, svec);
    // D3: reduce_sym (288) + matvec2 (256)
    red_mv<<<dim3(544), dim3(256), 0, stream>>>(part, Gb, Wkb, Wvb, svec, kv1, wvs);
    // D4: S1 = Wv G (256 gemm) + dual matvec (256: r1 = Wq^T kv1, r2 = Wq^T bk)
    gemm_bt<64, 64, 0, 4, 3, bf16_t><<<dim3(512), dim3(256), 0, stream>>>(
        Wvb, Gb, S1b, nf, H, H, H, H, 1.0f, 256,
        nf, nf, nf, nf, 0.f, WqTb, kv1, bk, nf, nf, r1, r2, 1.0f);
    // D5: Ut = (1/32)(S1 @ W2T^T + bv r1^T + (wvs + N bv) r2^T) (256 gemm)
    //     + cvec = (1/32)(S1 q1 + bv (kv1.bq) + (wvs+N bv)(bk.bq)) (256)
    gemm_bt<64, 64, 3, 4, 4, bf16_t><<<dim3(512), dim3(256), 0, stream>>>(
        S1b, W2Tb, Utb, nf, H, H, H, H, inv32, 256,
        bv, r1, wvs, r2, (float)SEQ, S1b, q1, bq, kv1, bk, cvec, nfm, inv32);
    // D6: out = xb Ut^T + cvec (fp32; XCD-swizzled)
    gemm_bt<128, 128, 1, 2, 0, float><<<dim3(512), dim3(256), 0, stream>>>(
        xb, Utb, out, cvec, SEQ, H, H, H, 1.0f, 1 << 30,
        nf, nf, nf, nf, 0.f, nullptr, nf, nf, nf, nf, nfm, nfm, 0.f);
}